// Round 14
// baseline (202.902 us; speedup 1.0000x reference)
//
#include <hip/hip_runtime.h>
#include <cstdint>
#include <cstddef>

typedef __bf16 bf16x8 __attribute__((ext_vector_type(8)));
typedef float f32x4 __attribute__((ext_vector_type(4)));
typedef unsigned short ushort8 __attribute__((ext_vector_type(8)));

#define OUT_DIM 4096
#define IN_DIM 4096
#define NT 128  // K tiles of 32

// ---------------- helpers ----------------

__device__ __forceinline__ unsigned short f2bf(float f) {
  unsigned u = __float_as_uint(f);
  return (unsigned short)((u + 0x7FFFu + ((u >> 16) & 1u)) >> 16);
}

__device__ __forceinline__ void async_copy16(const void* g, void* l) {
  __builtin_amdgcn_global_load_lds(
      (const __attribute__((address_space(1))) unsigned int*)g,
      (__attribute__((address_space(3))) unsigned int*)l, 16, 0, 0);
}

// ---------------- weight build (verified rounds 9/11/13) ----------------

__global__ __launch_bounds__(256) void prep_kernel(
    const int* __restrict__ packed, const float* __restrict__ scales,
    unsigned short* __restrict__ wb, const float* __restrict__ x,
    unsigned short* __restrict__ xb) {
  int b = blockIdx.x;
  if (b < 8192) {
    int idx = b * 256 + threadIdx.x;  // 4 packed int32 bytes -> 8 weights
    int4 p = reinterpret_cast<const int4*>(packed)[idx];
    float s = scales[idx >> 9];  // 512 int4-groups per row
    ushort8 o;
    o[0] = f2bf((float)((p.x & 15) - 8) * s);
    o[1] = f2bf((float)(((p.x >> 4) & 15) - 8) * s);
    o[2] = f2bf((float)((p.y & 15) - 8) * s);
    o[3] = f2bf((float)(((p.y >> 4) & 15) - 8) * s);
    o[4] = f2bf((float)((p.z & 15) - 8) * s);
    o[5] = f2bf((float)(((p.z >> 4) & 15) - 8) * s);
    o[6] = f2bf((float)((p.w & 15) - 8) * s);
    o[7] = f2bf((float)(((p.w >> 4) & 15) - 8) * s);
    *reinterpret_cast<ushort8*>(&wb[(size_t)idx * 8]) = o;
  } else {
    int i = (b - 8192) * 256 + threadIdx.x;
    float4 a = reinterpret_cast<const float4*>(x)[2 * i];
    float4 c = reinterpret_cast<const float4*>(x)[2 * i + 1];
    ushort8 o;
    o[0] = f2bf(a.x); o[1] = f2bf(a.y); o[2] = f2bf(a.z); o[3] = f2bf(a.w);
    o[4] = f2bf(c.x); o[5] = f2bf(c.y); o[6] = f2bf(c.z); o[7] = f2bf(c.w);
    *reinterpret_cast<ushort8*>(&xb[(size_t)i * 8]) = o;
  }
}

__global__ __launch_bounds__(256) void scatter_pk_kernel(
    const float* __restrict__ vals, const int* __restrict__ rows,
    const int* __restrict__ cols, unsigned short* __restrict__ wb, int nnz) {
  int i = blockIdx.x * 256 + threadIdx.x;
  if (i >= nnz) return;
  size_t idx = (size_t)rows[i] * IN_DIM + cols[i];
  unsigned int* word = (unsigned int*)(wb + (idx & ~(size_t)1));
  unsigned short h = f2bf(vals[i]);
  unsigned int data = (idx & 1) ? ((unsigned)h << 16) : (unsigned)h;
  asm volatile("global_atomic_pk_add_bf16 %0, %1, off"
               :: "v"(word), "v"(data) : "memory");
}

// ---------------- GEMM: C[N][O] = A[N][K] * B[O][K]^T, 128x256 tile --------
// TLP variant: 48 KiB LDS -> 2 blocks/CU, 512 blocks = all 256 CUs busy.
// Mechanism (m114, m97@~3blk/CU): co-resident blocks are NOT barrier-synced
// with each other, so one block's DS/barrier phases overlap the other's
// MFMA clusters — the cross-block overlap that every intra-block schedule
// variant (rounds 6-10, all null) failed to create under wave lockstep.
//
// Geometry: BM=128, BN=256, BK=32; 8 waves 2M x 4N, per-wave 64x64 out
// (acc[4][4] = 64 VGPR; <=128 total for 4 waves/SIMD). NT=128 K-tiles.
// LDS: 2 buf x (A [128][32] 8KB + B [256][32] 16KB) = 48 KiB.
//
// Per K-tile t (buf=t%2): issue STAGE A,B(t+1)->buf^1 (3 loads/thread);
// vmcnt(3) [t's 3 complete, t+1's 3 in flight - never 0 in-loop, T4];
// barrier; read 4 A-frags + 4 B-frags; lgkm(0); 16 MFMA; barrier.
// WAR: buf^1 fully read + drained (lgkm0) + barrier before its re-stage.
// Tail: t=127 stages clamped t=127 into never-read slots; final drain.
// Swizzle sigma(row)=(row>>1)&3 on 16B slots, both-sides (rule #21).

#define SBA(buf) ((buf) * 24576)
#define SBB(buf) ((buf) * 24576 + 8192)

#define STAGE_A(buf, kt)                                                    \
  async_copy16(gA + (kt) * 32,                                              \
               (char*)lds + SBA(buf) + wave * 1024)

#define STAGE_B(buf, kt)                                                    \
  do {                                                                      \
    const unsigned short* g_ = gB + (kt) * 32;                              \
    char* l_ = (char*)lds + SBB(buf) + wave * 1024;                         \
    async_copy16(g_, l_);                                                   \
    async_copy16(g_ + 128 * IN_DIM, l_ + 8192);                             \
  } while (0)

#define MFMA_ __builtin_amdgcn_mfma_f32_16x16x32_bf16

#define LDA4(BUF)                                                           \
  a0 = *(const bf16x8*)(ldsc + (laneA + SBA(BUF) + 0));                     \
  a1 = *(const bf16x8*)(ldsc + (laneA + SBA(BUF) + 1024));                  \
  a2 = *(const bf16x8*)(ldsc + (laneA + SBA(BUF) + 2048));                  \
  a3 = *(const bf16x8*)(ldsc + (laneA + SBA(BUF) + 3072))

#define LDB4(BUF)                                                           \
  b0 = *(const bf16x8*)(ldsc + (laneB + SBB(BUF) + 0));                     \
  b1 = *(const bf16x8*)(ldsc + (laneB + SBB(BUF) + 1024));                  \
  b2 = *(const bf16x8*)(ldsc + (laneB + SBB(BUF) + 2048));                  \
  b3 = *(const bf16x8*)(ldsc + (laneB + SBB(BUF) + 3072))

// 16 independent MFMA (each acc element touched once per K-tile)
#define MM16                                                                \
  acc[0][0] = MFMA_(a0, b0, acc[0][0], 0, 0, 0);                            \
  acc[0][1] = MFMA_(a0, b1, acc[0][1], 0, 0, 0);                            \
  acc[0][2] = MFMA_(a0, b2, acc[0][2], 0, 0, 0);                            \
  acc[0][3] = MFMA_(a0, b3, acc[0][3], 0, 0, 0);                            \
  acc[1][0] = MFMA_(a1, b0, acc[1][0], 0, 0, 0);                            \
  acc[1][1] = MFMA_(a1, b1, acc[1][1], 0, 0, 0);                            \
  acc[1][2] = MFMA_(a1, b2, acc[1][2], 0, 0, 0);                            \
  acc[1][3] = MFMA_(a1, b3, acc[1][3], 0, 0, 0);                            \
  acc[2][0] = MFMA_(a2, b0, acc[2][0], 0, 0, 0);                            \
  acc[2][1] = MFMA_(a2, b1, acc[2][1], 0, 0, 0);                            \
  acc[2][2] = MFMA_(a2, b2, acc[2][2], 0, 0, 0);                            \
  acc[2][3] = MFMA_(a2, b3, acc[2][3], 0, 0, 0);                            \
  acc[3][0] = MFMA_(a3, b0, acc[3][0], 0, 0, 0);                            \
  acc[3][1] = MFMA_(a3, b1, acc[3][1], 0, 0, 0);                            \
  acc[3][2] = MFMA_(a3, b2, acc[3][2], 0, 0, 0);                            \
  acc[3][3] = MFMA_(a3, b3, acc[3][3], 0, 0, 0)

#define MINC(x) ((x) < NT ? (x) : (NT - 1))

#define TILE(BUF, tS)                                                       \
  do {                                                                      \
    STAGE_A(1 - (BUF), tS);                                                 \
    STAGE_B(1 - (BUF), tS);                                                 \
    asm volatile("s_waitcnt vmcnt(3)" ::: "memory");                        \
    __builtin_amdgcn_s_barrier();                                           \
    LDA4(BUF);                                                              \
    LDB4(BUF);                                                              \
    asm volatile("s_waitcnt lgkmcnt(0)" ::: "memory");                      \
    __builtin_amdgcn_s_setprio(1);                                          \
    MM16;                                                                   \
    __builtin_amdgcn_s_setprio(0);                                          \
    __builtin_amdgcn_s_barrier();                                           \
  } while (0)

__global__ __launch_bounds__(512, 4) void gemm_kernel(
    const unsigned short* __restrict__ A,  // [4096][4096] bf16 (x)
    const unsigned short* __restrict__ B,  // [4096][4096] bf16 (W)
    float* __restrict__ C) {               // [4096][4096] fp32
  __shared__ __align__(16) unsigned short lds[24576];  // 48 KiB
  const char* ldsc = (const char*)lds;

  // XCD-chunked mapping: 512 blocks, 64/XCD as an 8bm x 8bn chunk.
  const int bid = blockIdx.x;
  const int xcd = bid & 7, i_ = bid >> 3;
  const int bm = (xcd >> 1) * 8 + (i_ >> 3);   // 0..31 (M tiles of 128)
  const int bn = (xcd & 1) * 8 + (i_ & 7);     // 0..15 (N tiles of 256)
  const int m0 = bm * 128, n0 = bn * 256;

  const int tid = threadIdx.x;
  const int wave = tid >> 6, lane = tid & 63;
  const int wm = wave >> 2, wn = wave & 3;  // 2M x 4N wave grid, 64x64 each
  const int lrow = lane & 15, lk = lane >> 4;

  // staging: thread -> chunk tid: row r0=tid>>2 (0..127), phys slot tid&3.
  // SOURCE slot pre-swizzled (rule #21); sigma(r0+128)==sigma(r0) for B.
  const int r0 = tid >> 2, s0 = tid & 3;
  const int s0s = s0 ^ ((r0 >> 1) & 3);
  const unsigned short* gA = A + (size_t)(m0 + r0) * IN_DIM + s0s * 8;
  const unsigned short* gB = B + (size_t)(n0 + r0) * IN_DIM + s0s * 8;

  // per-lane LDS byte bases (swizzle folded into lks)
  const int lks = lk ^ ((lrow >> 1) & 3);
  const int laneA = (wm * 64 + lrow) * 64 + lks * 16;
  const int laneB = (wn * 64 + lrow) * 64 + lks * 16;

  f32x4 acc[4][4];
#pragma unroll
  for (int mi = 0; mi < 4; ++mi)
#pragma unroll
    for (int ni = 0; ni < 4; ++ni) acc[mi][ni] = (f32x4){0.f, 0.f, 0.f, 0.f};

  bf16x8 a0, a1, a2, a3, b0, b1, b2, b3;

  // prologue: tile 0 -> buf0 (3 loads/thread).
  STAGE_A(0, 0);
  STAGE_B(0, 0);

#pragma unroll 1
  for (int p = 0; p < NT / 2; ++p) {
    TILE(0, MINC(2 * p + 1));
    TILE(1, MINC(2 * p + 2));
  }
  // drain DMA before epilogue/endpgm
  asm volatile("s_waitcnt vmcnt(0) lgkmcnt(0)" ::: "memory");

  // epilogue: D mapping col=lane&15, row=(lane>>4)*4+reg
#pragma unroll
  for (int mi = 0; mi < 4; ++mi)
#pragma unroll
    for (int ni = 0; ni < 4; ++ni) {
      int m = m0 + wm * 64 + mi * 16 + lk * 4;
      int n = n0 + wn * 64 + ni * 16 + lrow;
      float* cp = &C[(size_t)m * OUT_DIM + n];
#pragma unroll
      for (int r = 0; r < 4; ++r) cp[(size_t)r * OUT_DIM] = acc[mi][ni][r];
    }
}

// ---------------- launch ----------------

extern "C" void kernel_launch(void* const* d_in, const int* in_sizes, int n_in,
                              void* d_out, int out_size, void* d_ws, size_t ws_size,
                              hipStream_t stream) {
  const float* x      = (const float*)d_in[0];
  const int*   packed = (const int*)d_in[1];
  const float* scales = (const float*)d_in[2];
  const float* vals   = (const float*)d_in[3];
  const int*   rows   = (const int*)d_in[4];
  const int*   cols   = (const int*)d_in[5];
  float* out = (float*)d_out;

  const int nnz = in_sizes[3];

  // ws: [0,32MB) W bf16 | [32,64MB) X bf16
  char* ws = (char*)d_ws;
  const size_t MB = 1024 * 1024;
  unsigned short* Wb = (unsigned short*)ws;
  unsigned short* Xb = (unsigned short*)(ws + 32 * MB);

  // 1) merged dequant (blocks 0-8191) + x cvt (blocks 8192-16383)
  prep_kernel<<<16384, 256, 0, stream>>>(packed, scales, Wb, x, Xb);
  // 2) outlier residual via HW packed-bf16 atomic add
  scatter_pk_kernel<<<(nnz + 255) / 256, 256, 0, stream>>>(vals, rows, cols, Wb, nnz);
  // 3) bf16 MFMA GEMM: out = Xb (4096x4096) * Wb^T, 2 blocks/CU
  gemm_kernel<<<512, 512, 0, stream>>>(Xb, Wb, out);
}

// Round 15
// 181.431 us; speedup vs baseline: 1.1183x; 1.1183x over previous
//
#include <hip/hip_runtime.h>
#include <cstdint>
#include <cstddef>

typedef __bf16 bf16x8 __attribute__((ext_vector_type(8)));
typedef float f32x4 __attribute__((ext_vector_type(4)));
typedef unsigned short ushort8 __attribute__((ext_vector_type(8)));

#define OUT_DIM 4096
#define IN_DIM 4096
#define NT 64  // K tiles of 64

// ---------------- helpers ----------------

__device__ __forceinline__ unsigned short f2bf(float f) {
  unsigned u = __float_as_uint(f);
  return (unsigned short)((u + 0x7FFFu + ((u >> 16) & 1u)) >> 16);
}

__device__ __forceinline__ void async_copy16(const void* g, void* l) {
  __builtin_amdgcn_global_load_lds(
      (const __attribute__((address_space(1))) unsigned int*)g,
      (__attribute__((address_space(3))) unsigned int*)l, 16, 0, 0);
}

// ---------------- weight build (verified rounds 9/11/13) ----------------

// merged: blocks [0,8192) = int4 dequant -> bf16 Wb; blocks [8192,16384) =
// x fp32 -> bf16 Xb. One launch instead of two.
__global__ __launch_bounds__(256) void prep_kernel(
    const int* __restrict__ packed, const float* __restrict__ scales,
    unsigned short* __restrict__ wb, const float* __restrict__ x,
    unsigned short* __restrict__ xb) {
  int b = blockIdx.x;
  if (b < 8192) {
    int idx = b * 256 + threadIdx.x;  // 4 packed int32 bytes -> 8 weights
    int4 p = reinterpret_cast<const int4*>(packed)[idx];
    float s = scales[idx >> 9];  // 512 int4-groups per row
    ushort8 o;
    o[0] = f2bf((float)((p.x & 15) - 8) * s);
    o[1] = f2bf((float)(((p.x >> 4) & 15) - 8) * s);
    o[2] = f2bf((float)((p.y & 15) - 8) * s);
    o[3] = f2bf((float)(((p.y >> 4) & 15) - 8) * s);
    o[4] = f2bf((float)((p.z & 15) - 8) * s);
    o[5] = f2bf((float)(((p.z >> 4) & 15) - 8) * s);
    o[6] = f2bf((float)((p.w & 15) - 8) * s);
    o[7] = f2bf((float)(((p.w >> 4) & 15) - 8) * s);
    *reinterpret_cast<ushort8*>(&wb[(size_t)idx * 8]) = o;
  } else {
    int i = (b - 8192) * 256 + threadIdx.x;
    float4 a = reinterpret_cast<const float4*>(x)[2 * i];
    float4 c = reinterpret_cast<const float4*>(x)[2 * i + 1];
    ushort8 o;
    o[0] = f2bf(a.x); o[1] = f2bf(a.y); o[2] = f2bf(a.z); o[3] = f2bf(a.w);
    o[4] = f2bf(c.x); o[5] = f2bf(c.y); o[6] = f2bf(c.z); o[7] = f2bf(c.w);
    *reinterpret_cast<ushort8*>(&xb[(size_t)i * 8]) = o;
  }
}

// outlier add via HW packed-bf16 atomic: one fire-and-forget instruction per
// outlier. Other lane adds +0.0 bf16 (exact identity; dequant never yields
// -0). Duplicates accumulate atomically.
__global__ __launch_bounds__(256) void scatter_pk_kernel(
    const float* __restrict__ vals, const int* __restrict__ rows,
    const int* __restrict__ cols, unsigned short* __restrict__ wb, int nnz) {
  int i = blockIdx.x * 256 + threadIdx.x;
  if (i >= nnz) return;
  size_t idx = (size_t)rows[i] * IN_DIM + cols[i];
  unsigned int* word = (unsigned int*)(wb + (idx & ~(size_t)1));
  unsigned short h = f2bf(vals[i]);
  unsigned int data = (idx & 1) ? ((unsigned)h << 16) : (unsigned)h;
  asm volatile("global_atomic_pk_add_bf16 %0, %1, off"
               :: "v"(word), "v"(data) : "memory");
}

// ---------------- GEMM: C[N][O] = A[N][K] * B[O][K]^T, 256x256 tile --------
// FINAL: round-9 quadrant kernel, the verified best of 7 variants
// (124.0 us, 1107 TF = 44% dense peak, MfmaUtil 49, 0 bank conflicts,
// VGPR 116). Failed alternatives (all measured): 8/4/8/4 read split (126),
// E/O reg prefetch (127.5), counted-lgkm (127.5), barrier-free skew
// (142.8), 32x32x16 MFMA (139.8, conflicts returned), 128x256 2-blk/CU TLP
// (135.5, FETCH +52%).
// Cycle model: 4714 cy/K-tile = DS wall ~2300 + MFMA wall ~2480 serialized
// by the 8-barrier wave lockstep; breaking it needs asm-level pipelining.
//
// 8 waves, QUADRANT schedule: B-frags for the FULL K=64 read once per
// K-tile (8 ds_read_b128, held in 32 VGPR); A streams 4 reads per phase.
// Ledger (per-wave FIFO, 2 loads/slab/wave; stages all -> buf^1):
//   P1: STAGE B-kh0(t+1); vmcnt(2); barrier; read B-all(8)+A-q0(4)
//       post-barrier (RAW); lgkm(0); MMQ0.
//   P2-P4: read A-q pre-barrier; STAGE next slab; barrier; lgkm(0); MMQ.
// Never drains vmcnt to 0 in-loop (T4). Swizzle sigma(row)=(row>>1)&3 on
// 16B slots, both-sides (rule #21) — 0 bank conflicts (measured r3-r13).

#define SB(buf, op, kh) ((((buf) * 4) + ((op) * 2) + (kh)) * 16384)

#define STAGE(buf, op, kh, kt)                                              \
  do {                                                                      \
    const unsigned short* gsrc_ =                                           \
        (op) ? (const unsigned short*)((const char*)gA + dBA) : gA;         \
    const unsigned short* g_ = gsrc_ + (kt) * 64 + (kh) * 32;               \
    unsigned short* l_ =                                                    \
        (unsigned short*)((char*)lds + SB(buf, op, kh)) + wave * 512;       \
    async_copy16(g_, l_);                                                   \
    async_copy16(g_ + 128 * IN_DIM, l_ + 4096);                             \
  } while (0)

#define MFMA_ __builtin_amdgcn_mfma_f32_16x16x32_bf16

// A quadrant Q: frags 2Q,2Q+1 from both kh slabs (4 reads)
#define LDAQ(BUF, Q)                                                        \
  a00 = *(const bf16x8*)(ldsc + (laneA + SB(BUF, 0, 0) + (2*(Q)) * 1024));  \
  a01 = *(const bf16x8*)(ldsc + (laneA + SB(BUF, 0, 0) + (2*(Q)+1) * 1024));\
  a10 = *(const bf16x8*)(ldsc + (laneA + SB(BUF, 0, 1) + (2*(Q)) * 1024));  \
  a11 = *(const bf16x8*)(ldsc + (laneA + SB(BUF, 0, 1) + (2*(Q)+1) * 1024))

#define LDB4(d0, d1, d2, d3, BUF, KS)                                       \
  d0 = *(const bf16x8*)(ldsc + (laneB + SB(BUF, 1, KS) + 0));               \
  d1 = *(const bf16x8*)(ldsc + (laneB + SB(BUF, 1, KS) + 1024));            \
  d2 = *(const bf16x8*)(ldsc + (laneB + SB(BUF, 1, KS) + 2048));            \
  d3 = *(const bf16x8*)(ldsc + (laneB + SB(BUF, 1, KS) + 3072))

// 16 MFMA: quadrant Q x K=64. kh0 cluster then kh1 (acc reuse distance 8).
#define MMQ(Q)                                                              \
  acc[2*(Q)+0][0] = MFMA_(a00, b00, acc[2*(Q)+0][0], 0, 0, 0);              \
  acc[2*(Q)+0][1] = MFMA_(a00, b01, acc[2*(Q)+0][1], 0, 0, 0);              \
  acc[2*(Q)+0][2] = MFMA_(a00, b02, acc[2*(Q)+0][2], 0, 0, 0);              \
  acc[2*(Q)+0][3] = MFMA_(a00, b03, acc[2*(Q)+0][3], 0, 0, 0);              \
  acc[2*(Q)+1][0] = MFMA_(a01, b00, acc[2*(Q)+1][0], 0, 0, 0);              \
  acc[2*(Q)+1][1] = MFMA_(a01, b01, acc[2*(Q)+1][1], 0, 0, 0);              \
  acc[2*(Q)+1][2] = MFMA_(a01, b02, acc[2*(Q)+1][2], 0, 0, 0);              \
  acc[2*(Q)+1][3] = MFMA_(a01, b03, acc[2*(Q)+1][3], 0, 0, 0);              \
  acc[2*(Q)+0][0] = MFMA_(a10, b10, acc[2*(Q)+0][0], 0, 0, 0);              \
  acc[2*(Q)+0][1] = MFMA_(a10, b11, acc[2*(Q)+0][1], 0, 0, 0);              \
  acc[2*(Q)+0][2] = MFMA_(a10, b12, acc[2*(Q)+0][2], 0, 0, 0);              \
  acc[2*(Q)+0][3] = MFMA_(a10, b13, acc[2*(Q)+0][3], 0, 0, 0);              \
  acc[2*(Q)+1][0] = MFMA_(a11, b10, acc[2*(Q)+1][0], 0, 0, 0);              \
  acc[2*(Q)+1][1] = MFMA_(a11, b11, acc[2*(Q)+1][1], 0, 0, 0);              \
  acc[2*(Q)+1][2] = MFMA_(a11, b12, acc[2*(Q)+1][2], 0, 0, 0);              \
  acc[2*(Q)+1][3] = MFMA_(a11, b13, acc[2*(Q)+1][3], 0, 0, 0)

#define PH1(BUF, tS)                                                        \
  do {                                                                      \
    STAGE(1 - (BUF), 1, 0, tS);                                             \
    asm volatile("s_waitcnt vmcnt(2)" ::: "memory");                        \
    __builtin_amdgcn_s_barrier();                                           \
    LDB4(b00, b01, b02, b03, BUF, 0);                                       \
    LDB4(b10, b11, b12, b13, BUF, 1);                                       \
    LDAQ(BUF, 0);                                                           \
    asm volatile("s_waitcnt lgkmcnt(0)" ::: "memory");                      \
    __builtin_amdgcn_s_setprio(1);                                          \
    MMQ(0);                                                                 \
    __builtin_amdgcn_s_setprio(0);                                          \
    __builtin_amdgcn_s_barrier();                                           \
  } while (0)

#define PHQ(BUF, Q, OP, KH, tS)                                             \
  do {                                                                      \
    LDAQ(BUF, Q);                                                           \
    STAGE(1 - (BUF), OP, KH, tS);                                           \
    __builtin_amdgcn_s_barrier();                                           \
    asm volatile("s_waitcnt lgkmcnt(0)" ::: "memory");                      \
    __builtin_amdgcn_s_setprio(1);                                          \
    MMQ(Q);                                                                 \
    __builtin_amdgcn_s_setprio(0);                                          \
    __builtin_amdgcn_s_barrier();                                           \
  } while (0)

#define MINC(x) ((x) < NT ? (x) : (NT - 1))

#define TILE(BUF, t)                                                        \
  do {                                                                      \
    PH1(BUF, MINC((t) + 1));                                                \
    PHQ(BUF, 1, 1, 1, MINC((t) + 1));                                       \
    PHQ(BUF, 2, 0, 0, MINC((t) + 1));                                       \
    PHQ(BUF, 3, 0, 1, MINC((t) + 1));                                       \
  } while (0)

__global__ __launch_bounds__(512, 2) void gemm_kernel(
    const unsigned short* __restrict__ A,  // [4096][4096] bf16 (x)
    const unsigned short* __restrict__ B,  // [4096][4096] bf16 (W)
    float* __restrict__ C) {               // [4096][4096] fp32
  __shared__ __align__(16) unsigned short lds[65536];  // 128 KiB
  const char* ldsc = (const char*)lds;

  // 4x8 (bm x bn) super-tile per XCD for L2 locality; 256%8==0 -> bijective
  const int bid = blockIdx.x;
  const int xcd = bid & 7, i_ = bid >> 3;
  const int bm = (xcd >> 1) * 4 + (i_ >> 3);
  const int bn = (xcd & 1) * 8 + (i_ & 7);
  const int m0 = bm * 256, n0 = bn * 256;

  const int tid = threadIdx.x;
  const int wave = tid >> 6, lane = tid & 63;
  const int wm = wave >> 2, wn = wave & 3;  // 2M x 4N wave grid
  const int lrow = lane & 15, lk = lane >> 4;

  // staging: chunk0 = tid -> (row=tid>>2, phys slot=tid&3); chunk1 = +128.
  // SOURCE slot pre-swizzled so swizzled-read sees correct data (rule #21).
  const int r0 = tid >> 2, s0 = tid & 3;
  const int s0s = s0 ^ ((r0 >> 1) & 3);
  const unsigned short* gA = A + (size_t)(m0 + r0) * IN_DIM + s0s * 8;
  // uniform (SGPR) byte delta to the B staging source
  const ptrdiff_t dBA = ((const char*)B - (const char*)A) +
                        (ptrdiff_t)(n0 - m0) * IN_DIM * 2;

  // per-lane LDS byte bases (swizzle folded into lks)
  const int lks = lk ^ ((lrow >> 1) & 3);
  const int laneA = (wm * 128 + lrow) * 64 + lks * 16;
  const int laneB = (wn * 64 + lrow) * 64 + lks * 16;

  f32x4 acc[8][4];
#pragma unroll
  for (int mi = 0; mi < 8; ++mi)
#pragma unroll
    for (int ni = 0; ni < 4; ++ni) acc[mi][ni] = (f32x4){0.f, 0.f, 0.f, 0.f};

  bf16x8 b00, b01, b02, b03, b10, b11, b12, b13;  // B K=64, per-tile
  bf16x8 a00, a01, a10, a11;                      // A quadrant, per-phase

  // prologue: all 4 slabs of tile 0 -> buf0 (FIFO order B0,B1,A0,A1 matches
  // the steady-state wait arithmetic; separators pin issue order).
  STAGE(0, 1, 0, 0);
  asm volatile("" ::: "memory");
  STAGE(0, 1, 1, 0);
  asm volatile("" ::: "memory");
  STAGE(0, 0, 0, 0);
  asm volatile("" ::: "memory");
  STAGE(0, 0, 1, 0);
  // no wait here: PH1(t=0)'s vmcnt(2)+barrier gates the first reads.

#pragma unroll 1
  for (int p = 0; p < NT / 2; ++p) {
    TILE(0, 2 * p);
    TILE(1, 2 * p + 1);
  }
  // drain DMA before epilogue/endpgm
  asm volatile("s_waitcnt vmcnt(0) lgkmcnt(0)" ::: "memory");

  // epilogue: D mapping col=lane&15, row=(lane>>4)*4+reg
#pragma unroll
  for (int mi = 0; mi < 8; ++mi)
#pragma unroll
    for (int ni = 0; ni < 4; ++ni) {
      int m = m0 + wm * 128 + mi * 16 + lk * 4;
      int n = n0 + wn * 64 + ni * 16 + lrow;
      float* cp = &C[(size_t)m * OUT_DIM + n];
#pragma unroll
      for (int r = 0; r < 4; ++r) cp[(size_t)r * OUT_DIM] = acc[mi][ni][r];
    }
}

// ---------------- launch ----------------

extern "C" void kernel_launch(void* const* d_in, const int* in_sizes, int n_in,
                              void* d_out, int out_size, void* d_ws, size_t ws_size,
                              hipStream_t stream) {
  const float* x      = (const float*)d_in[0];
  const int*   packed = (const int*)d_in[1];
  const float* scales = (const float*)d_in[2];
  const float* vals   = (const float*)d_in[3];
  const int*   rows   = (const int*)d_in[4];
  const int*   cols   = (const int*)d_in[5];
  float* out = (float*)d_out;

  const int nnz = in_sizes[3];

  // ws: [0,32MB) W bf16 | [32,64MB) X bf16
  char* ws = (char*)d_ws;
  const size_t MB = 1024 * 1024;
  unsigned short* Wb = (unsigned short*)ws;
  unsigned short* Xb = (unsigned short*)(ws + 32 * MB);

  // 1) merged dequant (blocks 0-8191) + x cvt (blocks 8192-16383)
  prep_kernel<<<16384, 256, 0, stream>>>(packed, scales, Wb, x, Xb);
  // 2) outlier residual via HW packed-bf16 atomic add
  scatter_pk_kernel<<<(nnz + 255) / 256, 256, 0, stream>>>(vals, rows, cols, Wb, nnz);
  // 3) bf16 MFMA GEMM: out = Xb (4096x4096) * Wb^T
  gemm_kernel<<<256, 512, 0, stream>>>(Xb, Wb, out);
}